// Round 5
// baseline (187.957 us; speedup 1.0000x reference)
//
#include <hip/hip_runtime.h>
#include <hip/hip_bf16.h>

// RAYEN ConstraintModule fused kernel for MI355X (gfx950).
// B=32768, IN_DIM=256, N=K=128, M_LIN=1024, QC=16. bf16 buffers (detector-routed).
// R4: barrier-free B-operand streaming. R3's LDS panel pipeline was defeated by
// __syncthreads() draining vmcnt(0) every panel (guide: barrier drain stall).
// Now each wave streams its own B-fragments global->register with an explicit
// 3-deep statically-named prefetch pipeline; compiler emits counted vmcnt waits;
// no barriers inside the streaming loops. rho kept twice: swizzled bf16 (MFMA A)
// and padded f32 [64][129] (conflict-free rv reads).

typedef __attribute__((ext_vector_type(8))) short short8;
typedef __attribute__((ext_vector_type(4))) float f32x4;

__device__ __forceinline__ float bf2f(unsigned short u) {
    union { unsigned int i; float f; } v; v.i = ((unsigned int)u) << 16; return v.f;
}
__device__ __forceinline__ unsigned short f2bf(float f) {
    union { float f; unsigned int i; } v; v.f = f;
    unsigned int r = v.i + 0x7FFFu + ((v.i >> 16) & 1u);  // RNE
    return (unsigned short)(r >> 16);
}

template<int DT>
__device__ __forceinline__ short8 ld8(const void* p, size_t i) {
    if constexpr (DT == 1) {
        return *reinterpret_cast<const short8*>(reinterpret_cast<const unsigned short*>(p) + i);
    } else {
        const float* f = reinterpret_cast<const float*>(p) + i;
        short8 r;
#pragma unroll
        for (int j = 0; j < 8; ++j) r[j] = (short)f2bf(f[j]);
        return r;
    }
}
template<int DT>
__device__ __forceinline__ float ldf(const void* p, int i) {
    if constexpr (DT == 1) return bf2f(reinterpret_cast<const unsigned short*>(p)[i]);
    else return reinterpret_cast<const float*>(p)[i];
}

__device__ __forceinline__ void glds16(const void* g, void* l) {
    __builtin_amdgcn_global_load_lds(
        (const __attribute__((address_space(1))) void*)g,
        (__attribute__((address_space(3))) void*)l, 16, 0, 0);
}

__global__ void detect_dtype(const unsigned short* __restrict__ x, int* __restrict__ flag) {
    __shared__ int cnt;
    if (threadIdx.x == 0) cnt = 0;
    __syncthreads();
    float a = fabsf(bf2f(x[threadIdx.x]));
    int ok = (a > 1e-3f && a < 1e2f) ? 1 : 0;
    atomicAdd(&cnt, ok);
    __syncthreads();
    if (threadIdx.x == 0) *flag = (cnt > 200) ? 1 : 0;  // 1 = bf16, 0 = f32
}

// ---- streaming step macros (static buffers, compile-time step index) ----

// D step: consume PF (4 B-frags), update dmax; prefetch step T+3.
#define D_STEP(PF, T) do {                                                              \
    f32x4 acc_[4];                                                                      \
    _Pragma("unroll") for (int rt = 0; rt < 4; ++rt)                                    \
        _Pragma("unroll") for (int e = 0; e < 4; ++e) acc_[rt][e] = 0.f;                \
    _Pragma("unroll") for (int kb = 0; kb < 4; ++kb)                                    \
        _Pragma("unroll") for (int rt = 0; rt < 4; ++rt)                                \
            acc_[rt] = __builtin_amdgcn_mfma_f32_16x16x32_bf16(af2[rt][kb], PF[kb], acc_[rt], 0, 0, 0); \
    _Pragma("unroll") for (int rt = 0; rt < 4; ++rt)                                    \
        _Pragma("unroll") for (int e = 0; e < 4; ++e)                                   \
            dmax[rt][e] = fmaxf(dmax[rt][e], acc_[rt][e]);                              \
    if ((T) + 3 < 16) {                                                                 \
        _Pragma("unroll") for (int kb = 0; kb < 4; ++kb)                                \
            PF[kb] = ld8<DT>(Dp, (size_t)(((T) + 3) * 64) * 128 + dm_base + kb * 32);   \
    }                                                                                   \
} while (0)

// delta step S (0..31): q-group qg=S>>3 (wave's q = qg*4+w), t=S&7 (k_out block).
#define Q_STEP(PF, S) do {                                                              \
    float rv_[4][4];                                                                    \
    _Pragma("unroll") for (int rt = 0; rt < 4; ++rt)                                    \
        _Pragma("unroll") for (int e = 0; e < 4; ++e)                                   \
            rv_[rt][e] = lds_rvf[rt * 16 + hi * 4 + e][((S) & 7) * 16 + lo];            \
    f32x4 acc_[4];                                                                      \
    _Pragma("unroll") for (int rt = 0; rt < 4; ++rt)                                    \
        _Pragma("unroll") for (int e = 0; e < 4; ++e) acc_[rt][e] = 0.f;                \
    _Pragma("unroll") for (int kb = 0; kb < 4; ++kb)                                    \
        _Pragma("unroll") for (int rt = 0; rt < 4; ++rt)                                \
            acc_[rt] = __builtin_amdgcn_mfma_f32_16x16x32_bf16(af2[rt][kb], PF[kb], acc_[rt], 0, 0, 0); \
    _Pragma("unroll") for (int rt = 0; rt < 4; ++rt)                                    \
        _Pragma("unroll") for (int e = 0; e < 4; ++e)                                   \
            qsum[rt][e] += acc_[rt][e] * rv_[rt][e];                                    \
    if (((S) & 7) == 7) {                                                               \
        _Pragma("unroll") for (int rt = 0; rt < 4; ++rt)                                \
            _Pragma("unroll") for (int e = 0; e < 4; ++e) {                             \
                float s_ = qsum[rt][e];                                                 \
                s_ += __shfl_xor(s_, 1); s_ += __shfl_xor(s_, 2);                       \
                s_ += __shfl_xor(s_, 4); s_ += __shfl_xor(s_, 8);                       \
                if (lo == 0) lds_quad[rt * 16 + hi * 4 + e][(((S) >> 3) << 2) | w] = s_;\
                qsum[rt][e] = 0.f;                                                      \
            }                                                                           \
    }                                                                                   \
    if ((S) + 3 < 32) {                                                                 \
        _Pragma("unroll") for (int kb = 0; kb < 4; ++kb)                                \
            PF[kb] = ld8<DT>(dltp,                                                      \
                (size_t)((((S) + 3) >> 3) * 4) * 16384 + (size_t)((((S) + 3) & 7) * 16) * 128 \
                + dq_base + kb * 32);                                                   \
    }                                                                                   \
} while (0)

template<int DT>
__global__ __launch_bounds__(256, 2) void rayen_fused(
    const void* __restrict__ xp,   const void* __restrict__ Wp,
    const void* __restrict__ bp,   const void* __restrict__ Dp,
    const void* __restrict__ ypp,  const void* __restrict__ z0p,
    const void* __restrict__ phip, const void* __restrict__ dltp,
    void* __restrict__ outp,       const int* __restrict__ flag)
{
    if (*flag != DT) return;

    __shared__ unsigned char lds_big[32768];    // x frags; later rho bf16 (16KB) aliased
    unsigned char* lds_rho = lds_big;
    __shared__ float lds_rvf[64][129];          // v_bar f32, padded (conflict-free)
    __shared__ float lds_nsq[64][4];
    __shared__ float lds_dmax[64][4];
    __shared__ float lds_quad[64][16];
    __shared__ float lds_lin[64][16];
    __shared__ float lds_alpha[64];

    const int tid = threadIdx.x;
    const int lane = tid & 63;
    const int w = tid >> 6;        // wave 0..3
    const int hi = lane >> 4;      // 0..3
    const int lo = lane & 15;      // 0..15
    const size_t row0 = (size_t)blockIdx.x * 64;

    const unsigned char* Xb = (const unsigned char*)xp;

    // per-lane streaming address bases (elements)
    const int dm_base = (w * 16 + lo) * 128 + hi * 8;            // D: + t*64*128 + kb*32
    const size_t dq_base = (size_t)w * 16384 + (size_t)lo * 128 + hi * 8; // delta: +qg*4*16384 + t*16*128 + kb*32

    // ---- stage x tile [64][256] bf16, fragment-major (frag f = rt*8+kb) ----
#pragma unroll
    for (int i = 0; i < 8; ++i) {
        int ch = i * 256 + tid;
        int row = ((ch >> 9) << 4) | (ch & 15);
        int off = (((ch >> 6) & 7) << 6) | (((ch >> 4) & 3) << 4);
        if constexpr (DT == 1)
            glds16(Xb + (row0 + row) * 512 + off, lds_big + ch * 16);
        else {
            short8 v = ld8<0>(Xb, (row0 + row) * 256 + (off >> 1));
            *reinterpret_cast<short8*>(lds_big + ch * 16) = v;
        }
    }

    // W fragments direct to regs (overlap x staging)
    short8 wf[2][8];
#pragma unroll
    for (int ct = 0; ct < 2; ++ct)
#pragma unroll
        for (int kb = 0; kb < 8; ++kb)
            wf[ct][kb] = ld8<DT>(Wp, (size_t)(w * 32 + ct * 16 + lo) * 256 + kb * 32 + hi * 8);

    __syncthreads();

    // ---- GEMM1: v[64][128] = x @ W^T; wave w: cols [w*32, w*32+32) ----
    f32x4 acc1[2][4];
#pragma unroll
    for (int c = 0; c < 2; ++c)
#pragma unroll
        for (int r = 0; r < 4; ++r)
#pragma unroll
            for (int e = 0; e < 4; ++e) acc1[c][r][e] = 0.f;

#pragma unroll
    for (int kb = 0; kb < 8; ++kb) {
        short8 af[4];
#pragma unroll
        for (int rt = 0; rt < 4; ++rt)
            af[rt] = *reinterpret_cast<const short8*>(
                lds_big + (((rt << 3) | kb) << 10) + lane * 16);
#pragma unroll
        for (int ct = 0; ct < 2; ++ct)
#pragma unroll
            for (int rt = 0; rt < 4; ++rt)
                acc1[ct][rt] = __builtin_amdgcn_mfma_f32_16x16x32_bf16(af[rt], wf[ct][kb], acc1[ct][rt], 0, 0, 0);
    }

    // bias + per-row sum of squares
    float bv[2];
#pragma unroll
    for (int ct = 0; ct < 2; ++ct) bv[ct] = ldf<DT>(bp, w * 32 + ct * 16 + lo);
#pragma unroll
    for (int rt = 0; rt < 4; ++rt)
#pragma unroll
        for (int reg = 0; reg < 4; ++reg) {
            float s = 0.f;
#pragma unroll
            for (int ct = 0; ct < 2; ++ct) {
                float v = acc1[ct][rt][reg] + bv[ct];
                acc1[ct][rt][reg] = v;
                s += v * v;
            }
            s += __shfl_xor(s, 1);
            s += __shfl_xor(s, 2);
            s += __shfl_xor(s, 4);
            s += __shfl_xor(s, 8);
            if (lo == 0) lds_nsq[rt * 16 + hi * 4 + reg][w] = s;
        }
    __syncthreads();   // x region dead after this barrier

    // ---- v_bar -> swizzled bf16 rho (aliased) + padded f32 copy ----
#pragma unroll
    for (int rt = 0; rt < 4; ++rt)
#pragma unroll
        for (int reg = 0; reg < 4; ++reg) {
            int row = rt * 16 + hi * 4 + reg;
            float nsq = lds_nsq[row][0] + lds_nsq[row][1] + lds_nsq[row][2] + lds_nsq[row][3];
            float rinv = 1.0f / fmaxf(sqrtf(nsq), 1e-12f);
#pragma unroll
            for (int ct = 0; ct < 2; ++ct) {
                int col = w * 32 + ct * 16 + lo;
                float vb = acc1[ct][rt][reg] * rinv;
                *reinterpret_cast<unsigned short*>(
                    lds_rho + row * 256 + ((col * 2) ^ ((row & 7) << 4))) = f2bf(vb);
                lds_rvf[row][col] = bf2f(f2bf(vb));   // match bf16 quantization
            }
        }
    __syncthreads();

    // ---- A-fragments (rho) resident: 64 VGPRs ----
    short8 af2[4][4];
#pragma unroll
    for (int rt = 0; rt < 4; ++rt)
#pragma unroll
        for (int kb = 0; kb < 4; ++kb) {
            int row = rt * 16 + lo;
            af2[rt][kb] = *reinterpret_cast<const short8*>(
                lds_rho + row * 256 + (((kb << 6) | (hi << 4)) ^ ((lo & 7) << 4)));
        }

    // ================= D segment: 16 steps, 3-deep register pipeline ==========
    f32x4 dmax[4];
#pragma unroll
    for (int rt = 0; rt < 4; ++rt)
#pragma unroll
        for (int e = 0; e < 4; ++e) dmax[rt][e] = -3e38f;

    short8 pf0[4], pf1[4], pf2[4];
#pragma unroll
    for (int kb = 0; kb < 4; ++kb) pf0[kb] = ld8<DT>(Dp, (size_t)(0 * 64) * 128 + dm_base + kb * 32);
#pragma unroll
    for (int kb = 0; kb < 4; ++kb) pf1[kb] = ld8<DT>(Dp, (size_t)(1 * 64) * 128 + dm_base + kb * 32);
#pragma unroll
    for (int kb = 0; kb < 4; ++kb) pf2[kb] = ld8<DT>(Dp, (size_t)(2 * 64) * 128 + dm_base + kb * 32);

    D_STEP(pf0, 0);  D_STEP(pf1, 1);  D_STEP(pf2, 2);
    D_STEP(pf0, 3);  D_STEP(pf1, 4);  D_STEP(pf2, 5);
    D_STEP(pf0, 6);  D_STEP(pf1, 7);  D_STEP(pf2, 8);
    D_STEP(pf0, 9);  D_STEP(pf1, 10); D_STEP(pf2, 11);
    D_STEP(pf0, 12); D_STEP(pf1, 13); D_STEP(pf2, 14);
    D_STEP(pf0, 15);

    // flush dmax (frees accumulators before delta segment)
#pragma unroll
    for (int rt = 0; rt < 4; ++rt)
#pragma unroll
        for (int reg = 0; reg < 4; ++reg) {
            float m = dmax[rt][reg];
            m = fmaxf(m, __shfl_xor(m, 1));
            m = fmaxf(m, __shfl_xor(m, 2));
            m = fmaxf(m, __shfl_xor(m, 4));
            m = fmaxf(m, __shfl_xor(m, 8));
            if (lo == 0) lds_dmax[rt * 16 + hi * 4 + reg][w] = m;
        }

    // ================= delta segment: 32 steps, 3-deep pipeline ==============
    f32x4 qsum[4];
#pragma unroll
    for (int rt = 0; rt < 4; ++rt)
#pragma unroll
        for (int e = 0; e < 4; ++e) qsum[rt][e] = 0.f;

#pragma unroll
    for (int kb = 0; kb < 4; ++kb) pf0[kb] = ld8<DT>(dltp, (size_t)0 * 16384 + (size_t)(0 * 16) * 128 + dq_base + kb * 32);
#pragma unroll
    for (int kb = 0; kb < 4; ++kb) pf1[kb] = ld8<DT>(dltp, (size_t)0 * 16384 + (size_t)(1 * 16) * 128 + dq_base + kb * 32);
#pragma unroll
    for (int kb = 0; kb < 4; ++kb) pf2[kb] = ld8<DT>(dltp, (size_t)0 * 16384 + (size_t)(2 * 16) * 128 + dq_base + kb * 32);

    Q_STEP(pf0, 0);  Q_STEP(pf1, 1);  Q_STEP(pf2, 2);
    Q_STEP(pf0, 3);  Q_STEP(pf1, 4);  Q_STEP(pf2, 5);
    Q_STEP(pf0, 6);  Q_STEP(pf1, 7);  Q_STEP(pf2, 8);
    Q_STEP(pf0, 9);  Q_STEP(pf1, 10); Q_STEP(pf2, 11);
    Q_STEP(pf0, 12); Q_STEP(pf1, 13); Q_STEP(pf2, 14);
    Q_STEP(pf0, 15); Q_STEP(pf1, 16); Q_STEP(pf2, 17);
    Q_STEP(pf0, 18); Q_STEP(pf1, 19); Q_STEP(pf2, 20);
    Q_STEP(pf0, 21); Q_STEP(pf1, 22); Q_STEP(pf2, 23);
    Q_STEP(pf0, 24); Q_STEP(pf1, 25); Q_STEP(pf2, 26);
    Q_STEP(pf0, 27); Q_STEP(pf1, 28); Q_STEP(pf2, 29);
    Q_STEP(pf0, 30); Q_STEP(pf1, 31);

    // ---- phi (wave 0): lin[b,q] = rho . phi_q ----
    if (w == 0) {
        f32x4 accp[4];
#pragma unroll
        for (int rt = 0; rt < 4; ++rt)
#pragma unroll
            for (int e = 0; e < 4; ++e) accp[rt][e] = 0.f;
#pragma unroll
        for (int kb = 0; kb < 4; ++kb) {
            short8 bp8 = ld8<DT>(phip, (size_t)lo * 128 + kb * 32 + hi * 8);
#pragma unroll
            for (int rt = 0; rt < 4; ++rt)
                accp[rt] = __builtin_amdgcn_mfma_f32_16x16x32_bf16(af2[rt][kb], bp8, accp[rt], 0, 0, 0);
        }
#pragma unroll
        for (int rt = 0; rt < 4; ++rt)
#pragma unroll
            for (int reg = 0; reg < 4; ++reg)
                lds_lin[rt * 16 + hi * 4 + reg][lo] = accp[rt][reg];
    }
    __syncthreads();

    // ---- per-row scalars: kappa, alpha ----
    if (tid < 64) {
        int row = tid;
        float nsq = lds_nsq[row][0] + lds_nsq[row][1] + lds_nsq[row][2] + lds_nsq[row][3];
        float norm = sqrtf(nsq);
        float kap = fmaxf(0.f, fmaxf(fmaxf(lds_dmax[row][0], lds_dmax[row][1]),
                                     fmaxf(lds_dmax[row][2], lds_dmax[row][3])));
#pragma unroll
        for (int q = 0; q < 16; ++q) {
            float kq = lds_lin[row][q] + sqrtf(fmaxf(lds_quad[row][q], 0.f));
            kap = fmaxf(kap, kq);
        }
        lds_alpha[row] = fminf(1.0f / kap, norm);   // kap==0 -> inf -> norm (matches ref)
    }
    __syncthreads();

    // ---- coalesced epilogue: y = z0 + alpha * v_bar + yp (NA_E = I) ----
#pragma unroll
    for (int i = 0; i < 4; ++i) {
        int idx = tid + i * 256;
        int row = idx >> 4;
        int col0 = (idx & 15) * 8;
        float alpha = lds_alpha[row];
        float yv[8];
#pragma unroll
        for (int j = 0; j < 8; ++j) {
            float vb = lds_rvf[row][col0 + j];
            yv[j] = ldf<DT>(z0p, col0 + j) + alpha * vb + ldf<DT>(ypp, col0 + j);
        }
        size_t obase = (row0 + row) * 128 + col0;
        if constexpr (DT == 1) {
            short8 pack;
#pragma unroll
            for (int j = 0; j < 8; ++j) pack[j] = (short)f2bf(yv[j]);
            *reinterpret_cast<short8*>(reinterpret_cast<unsigned short*>(outp) + obase) = pack;
        } else {
            f32x4 p0, p1;
#pragma unroll
            for (int j = 0; j < 4; ++j) { p0[j] = yv[j]; p1[j] = yv[4 + j]; }
            *reinterpret_cast<f32x4*>(reinterpret_cast<float*>(outp) + obase) = p0;
            *reinterpret_cast<f32x4*>(reinterpret_cast<float*>(outp) + obase + 4) = p1;
        }
    }
}

extern "C" void kernel_launch(void* const* d_in, const int* in_sizes, int n_in,
                              void* d_out, int out_size, void* d_ws, size_t ws_size,
                              hipStream_t stream) {
    const void* x    = d_in[0];
    const void* W    = d_in[1];
    const void* b    = d_in[2];
    const void* D    = d_in[3];
    // d_in[4] = NA_E (identity by construction; unused)
    const void* yp   = d_in[5];
    const void* z0   = d_in[6];
    const void* phi  = d_in[7];
    const void* dlt  = d_in[8];
    int* flag = reinterpret_cast<int*>(d_ws);

    const int B = in_sizes[0] / 256;    // 32768
    dim3 grid(B / 64), blk(256);

    detect_dtype<<<dim3(1), dim3(256), 0, stream>>>(
        reinterpret_cast<const unsigned short*>(x), flag);
    rayen_fused<1><<<grid, blk, 0, stream>>>(x, W, b, D, yp, z0, phi, dlt, d_out, flag);
    rayen_fused<0><<<grid, blk, 0, stream>>>(x, W, b, D, yp, z0, phi, dlt, d_out, flag);
}

// Round 6
// 147.677 us; speedup vs baseline: 1.2728x; 1.2728x over previous
//
#include <hip/hip_runtime.h>
#include <hip/hip_bf16.h>

// RAYEN ConstraintModule fused kernel for MI355X (gfx950).
// B=32768, IN_DIM=256, N=K=128, M_LIN=1024, QC=16. bf16 buffers (detector-routed).
// R5 = R3 structure (LDS panel streaming via global_load_lds, frag-major layout,
// no spills) with the panel-loop sync fixed per T3/T4: raw s_barrier + COUNTED
// s_waitcnt vmcnt(4) (never drain), 3-buffer rotation staging 2 panels ahead,
// ONE barrier per panel. R3's __syncthreads() was draining vmcnt(0) every panel,
// exposing full L2 latency per panel (the guide's barrier-drain stall).

typedef __attribute__((ext_vector_type(8))) short short8;
typedef __attribute__((ext_vector_type(4))) float f32x4;

__device__ __forceinline__ float bf2f(unsigned short u) {
    union { unsigned int i; float f; } v; v.i = ((unsigned int)u) << 16; return v.f;
}
__device__ __forceinline__ unsigned short f2bf(float f) {
    union { float f; unsigned int i; } v; v.f = f;
    unsigned int r = v.i + 0x7FFFu + ((v.i >> 16) & 1u);  // RNE
    return (unsigned short)(r >> 16);
}

template<int DT>
__device__ __forceinline__ short8 ld8(const void* p, size_t i) {
    if constexpr (DT == 1) {
        return *reinterpret_cast<const short8*>(reinterpret_cast<const unsigned short*>(p) + i);
    } else {
        const float* f = reinterpret_cast<const float*>(p) + i;
        short8 r;
#pragma unroll
        for (int j = 0; j < 8; ++j) r[j] = (short)f2bf(f[j]);
        return r;
    }
}
template<int DT>
__device__ __forceinline__ float ldf(const void* p, int i) {
    if constexpr (DT == 1) return bf2f(reinterpret_cast<const unsigned short*>(p)[i]);
    else return reinterpret_cast<const float*>(p)[i];
}

__device__ __forceinline__ void glds16(const void* g, void* l) {
    __builtin_amdgcn_global_load_lds(
        (const __attribute__((address_space(1))) void*)g,
        (__attribute__((address_space(3))) void*)l, 16, 0, 0);
}

__global__ void detect_dtype(const unsigned short* __restrict__ x, int* __restrict__ flag) {
    __shared__ int cnt;
    if (threadIdx.x == 0) cnt = 0;
    __syncthreads();
    float a = fabsf(bf2f(x[threadIdx.x]));
    int ok = (a > 1e-3f && a < 1e2f) ? 1 : 0;
    atomicAdd(&cnt, ok);
    __syncthreads();
    if (threadIdx.x == 0) *flag = (cnt > 200) ? 1 : 0;  // 1 = bf16, 0 = f32
}

// Stage one 16KB B-panel (64 rows x 256B) in fragment-major order:
// LDS chunk ch (16B): frag f = ch>>6 = w*4+kb, lane l = ch&63 (hi=l>>4, lo=l&15)
// holds global[row(p, w*16+lo)][kb*64 + hi*16 .. +15].
// Panels 0..15: D rows p*64+r. Panels 16..47: delta, q-interleaved:
// row r -> q = (pd>>3)*4 + (r>>4), k_out = (pd&7)*16 + (r&15).
template<int DT>
__device__ __forceinline__ void stage_panel(int p, unsigned char* buf, int tid,
                                            const unsigned char* Db, const unsigned char* Qb) {
#pragma unroll
    for (int i = 0; i < 4; ++i) {
        int ch = i * 256 + tid;
        int r   = ((ch >> 8) << 4) | (ch & 15);                       // panel row 0..63
        int off = (((ch >> 6) & 3) << 6) | (((ch >> 4) & 3) << 4);    // byte 0..255
        int gr; const unsigned char* base;
        if (p < 16) { base = Db; gr = p * 64 + r; }
        else {
            int pd = p - 16;
            base = Qb;
            gr = ((((pd >> 3) << 2) | (r >> 4)) << 7) | (((pd & 7) << 4) | (r & 15));
        }
        if constexpr (DT == 1) {
            glds16(base + (size_t)gr * 256 + off, buf + ch * 16);
        } else {
            short8 v = ld8<0>(base, (size_t)gr * 128 + (off >> 1));
            *reinterpret_cast<short8*>(buf + ch * 16) = v;
        }
    }
}

template<int DT>
__global__ __launch_bounds__(256, 2) void rayen_fused(
    const void* __restrict__ xp,   const void* __restrict__ Wp,
    const void* __restrict__ bp,   const void* __restrict__ Dp,
    const void* __restrict__ ypp,  const void* __restrict__ z0p,
    const void* __restrict__ phip, const void* __restrict__ dltp,
    void* __restrict__ outp,       const int* __restrict__ flag)
{
    if (*flag != DT) return;

    __shared__ unsigned char lds_big[49152];    // x frags (32KB) ; then 3x16KB panel bufs
    __shared__ unsigned char lds_rho[64 * 256]; // rho [64][256B], XOR-swizzled rows
    __shared__ float lds_nsq[64][4];
    __shared__ float lds_dmax[64][4];
    __shared__ float lds_quad[64][16];
    __shared__ float lds_lin[64][16];
    __shared__ float lds_alpha[64];

    const int tid = threadIdx.x;
    const int lane = tid & 63;
    const int w = tid >> 6;        // wave 0..3
    const int hi = lane >> 4;      // 0..3
    const int lo = lane & 15;      // 0..15
    const size_t row0 = (size_t)blockIdx.x * 64;

    const unsigned char* Xb = (const unsigned char*)xp;
    const unsigned char* Db = (const unsigned char*)Dp;
    const unsigned char* Qb = (const unsigned char*)dltp;

    // ---- stage x tile [64][256] bf16, fragment-major: frag f = rt*8+kb ----
#pragma unroll
    for (int i = 0; i < 8; ++i) {
        int ch = i * 256 + tid;
        int row = ((ch >> 9) << 4) | (ch & 15);
        int off = (((ch >> 6) & 7) << 6) | (((ch >> 4) & 3) << 4);   // byte in 512B row
        if constexpr (DT == 1)
            glds16(Xb + (row0 + row) * 512 + off, lds_big + ch * 16);
        else {
            short8 v = ld8<0>(Xb, (row0 + row) * 256 + (off >> 1));
            *reinterpret_cast<short8*>(lds_big + ch * 16) = v;
        }
    }

    // W fragments direct to regs (overlaps x staging)
    short8 wf[2][8];
#pragma unroll
    for (int ct = 0; ct < 2; ++ct)
#pragma unroll
        for (int kb = 0; kb < 8; ++kb)
            wf[ct][kb] = ld8<DT>(Wp, (size_t)(w * 32 + ct * 16 + lo) * 256 + kb * 32 + hi * 8);

    asm volatile("s_waitcnt vmcnt(0)" ::: "memory");
    __syncthreads();

    // ---- GEMM1: v[64][128] = x @ W^T; wave w: cols [w*32, w*32+32) ----
    f32x4 acc1[2][4];
#pragma unroll
    for (int c = 0; c < 2; ++c)
#pragma unroll
        for (int r = 0; r < 4; ++r)
#pragma unroll
            for (int e = 0; e < 4; ++e) acc1[c][r][e] = 0.f;

#pragma unroll
    for (int kb = 0; kb < 8; ++kb) {
        short8 af[4];
#pragma unroll
        for (int rt = 0; rt < 4; ++rt)
            af[rt] = *reinterpret_cast<const short8*>(
                lds_big + (((rt << 3) | kb) << 10) + lane * 16);
#pragma unroll
        for (int ct = 0; ct < 2; ++ct)
#pragma unroll
            for (int rt = 0; rt < 4; ++rt)
                acc1[ct][rt] = __builtin_amdgcn_mfma_f32_16x16x32_bf16(af[rt], wf[ct][kb], acc1[ct][rt], 0, 0, 0);
    }

    // bias + per-row sum of squares
    float bv[2];
#pragma unroll
    for (int ct = 0; ct < 2; ++ct) bv[ct] = ldf<DT>(bp, w * 32 + ct * 16 + lo);
#pragma unroll
    for (int rt = 0; rt < 4; ++rt)
#pragma unroll
        for (int reg = 0; reg < 4; ++reg) {
            float s = 0.f;
#pragma unroll
            for (int ct = 0; ct < 2; ++ct) {
                float v = acc1[ct][rt][reg] + bv[ct];
                acc1[ct][rt][reg] = v;
                s += v * v;
            }
            s += __shfl_xor(s, 1);
            s += __shfl_xor(s, 2);
            s += __shfl_xor(s, 4);
            s += __shfl_xor(s, 8);
            if (lo == 0) lds_nsq[rt * 16 + hi * 4 + reg][w] = s;
        }
    __syncthreads();   // x region dead after this point

    // ---- v_bar -> swizzled bf16 rho ----
#pragma unroll
    for (int rt = 0; rt < 4; ++rt)
#pragma unroll
        for (int reg = 0; reg < 4; ++reg) {
            int row = rt * 16 + hi * 4 + reg;
            float nsq = lds_nsq[row][0] + lds_nsq[row][1] + lds_nsq[row][2] + lds_nsq[row][3];
            float rinv = 1.0f / fmaxf(sqrtf(nsq), 1e-12f);
#pragma unroll
            for (int ct = 0; ct < 2; ++ct) {
                int col = w * 32 + ct * 16 + lo;
                unsigned short u = f2bf(acc1[ct][rt][reg] * rinv);
                *reinterpret_cast<unsigned short*>(
                    lds_rho + row * 256 + ((col * 2) ^ ((row & 7) << 4))) = u;
            }
        }
    __syncthreads();

    // ---- A-fragments (rho) resident: 64 VGPRs ----
    short8 af2[4][4];
#pragma unroll
    for (int rt = 0; rt < 4; ++rt)
#pragma unroll
        for (int kb = 0; kb < 4; ++kb) {
            int row = rt * 16 + lo;
            af2[rt][kb] = *reinterpret_cast<const short8*>(
                lds_rho + row * 256 + (((kb << 6) | (hi << 4)) ^ ((lo & 7) << 4)));
        }
    __syncthreads();   // af2 reads done; panel staging may overwrite lds_big

    // prime the panel pipeline: panels 0,1 into bufs 0,1 (4 glds/thread each)
    stage_panel<DT>(0, lds_big, tid, Db, Qb);
    stage_panel<DT>(1, lds_big + 16384, tid, Db, Qb);

    f32x4 dmax[4];
#pragma unroll
    for (int rt = 0; rt < 4; ++rt)
#pragma unroll
        for (int e = 0; e < 4; ++e) dmax[rt][e] = -3e38f;
    f32x4 qsum[4];
#pragma unroll
    for (int rt = 0; rt < 4; ++rt)
#pragma unroll
        for (int e = 0; e < 4; ++e) qsum[rt][e] = 0.f;

    // ---- panel loop: 16 D panels + 32 delta panels; ONE raw barrier/panel,
    //      counted vmcnt (T4), 3-buffer rotation staging 2 ahead ----
#pragma unroll 1
    for (int p = 0; p < 48; ++p) {
        if constexpr (DT == 1) {
            if (p < 47) { asm volatile("s_waitcnt vmcnt(4)" ::: "memory"); }
            else        { asm volatile("s_waitcnt vmcnt(0)" ::: "memory"); }
        } else {
            asm volatile("s_waitcnt lgkmcnt(0) vmcnt(0)" ::: "memory");
        }
        __builtin_amdgcn_s_barrier();
        __builtin_amdgcn_sched_barrier(0);

        // stage p+2 into the buffer consumed at p-1 (free: all waves passed barrier)
        if (p + 2 < 48)
            stage_panel<DT>(p + 2, lds_big + ((p + 2) % 3) * 16384, tid, Db, Qb);

        unsigned char* buf = lds_big + (p % 3) * 16384;
        f32x4 acc[4];
#pragma unroll
        for (int rt = 0; rt < 4; ++rt)
#pragma unroll
            for (int e = 0; e < 4; ++e) acc[rt][e] = 0.f;
#pragma unroll
        for (int kb = 0; kb < 4; ++kb) {
            short8 bf = *reinterpret_cast<const short8*>(
                buf + (((w << 2) | kb) << 10) + lane * 16);
#pragma unroll
            for (int rt = 0; rt < 4; ++rt)
                acc[rt] = __builtin_amdgcn_mfma_f32_16x16x32_bf16(af2[rt][kb], bf, acc[rt], 0, 0, 0);
        }

        if (p < 16) {
#pragma unroll
            for (int rt = 0; rt < 4; ++rt)
#pragma unroll
                for (int e = 0; e < 4; ++e) dmax[rt][e] = fmaxf(dmax[rt][e], acc[rt][e]);
        } else {
            int pd = p - 16;
            int kr = (pd & 7) << 4;
#pragma unroll
            for (int rt = 0; rt < 4; ++rt)
#pragma unroll
                for (int e = 0; e < 4; ++e) {
                    int row = rt * 16 + hi * 4 + e;
                    float rvv = bf2f(*reinterpret_cast<const unsigned short*>(
                        lds_rho + row * 256 + ((((kr + lo) * 2)) ^ ((row & 7) << 4))));
                    qsum[rt][e] += acc[rt][e] * rvv;
                }
            if ((pd & 7) == 7) {
#pragma unroll
                for (int rt = 0; rt < 4; ++rt)
#pragma unroll
                    for (int e = 0; e < 4; ++e) {
                        float s = qsum[rt][e];
                        s += __shfl_xor(s, 1);
                        s += __shfl_xor(s, 2);
                        s += __shfl_xor(s, 4);
                        s += __shfl_xor(s, 8);
                        if (lo == 0) lds_quad[rt * 16 + hi * 4 + e][((pd >> 3) << 2) | w] = s;
                        qsum[rt][e] = 0.f;
                    }
            }
        }
        // no second barrier: WAR protected by next iteration's barrier
    }

    // ---- dmax reduce ----
#pragma unroll
    for (int rt = 0; rt < 4; ++rt)
#pragma unroll
        for (int reg = 0; reg < 4; ++reg) {
            float m = dmax[rt][reg];
            m = fmaxf(m, __shfl_xor(m, 1));
            m = fmaxf(m, __shfl_xor(m, 2));
            m = fmaxf(m, __shfl_xor(m, 4));
            m = fmaxf(m, __shfl_xor(m, 8));
            if (lo == 0) lds_dmax[rt * 16 + hi * 4 + reg][w] = m;
        }

    // ---- phi (wave 0): lin[b,q] = rho . phi_q ----
    if (w == 0) {
        f32x4 accp[4];
#pragma unroll
        for (int rt = 0; rt < 4; ++rt)
#pragma unroll
            for (int e = 0; e < 4; ++e) accp[rt][e] = 0.f;
#pragma unroll
        for (int kb = 0; kb < 4; ++kb) {
            short8 bp8 = ld8<DT>(phip, (size_t)lo * 128 + kb * 32 + hi * 8);
#pragma unroll
            for (int rt = 0; rt < 4; ++rt)
                accp[rt] = __builtin_amdgcn_mfma_f32_16x16x32_bf16(af2[rt][kb], bp8, accp[rt], 0, 0, 0);
        }
#pragma unroll
        for (int rt = 0; rt < 4; ++rt)
#pragma unroll
            for (int reg = 0; reg < 4; ++reg)
                lds_lin[rt * 16 + hi * 4 + reg][lo] = accp[rt][reg];
    }
    __syncthreads();

    // ---- per-row scalars: kappa, alpha ----
    if (tid < 64) {
        int row = tid;
        float nsq = lds_nsq[row][0] + lds_nsq[row][1] + lds_nsq[row][2] + lds_nsq[row][3];
        float norm = sqrtf(nsq);
        float kap = fmaxf(0.f, fmaxf(fmaxf(lds_dmax[row][0], lds_dmax[row][1]),
                                     fmaxf(lds_dmax[row][2], lds_dmax[row][3])));
#pragma unroll
        for (int q = 0; q < 16; ++q) {
            float kq = lds_lin[row][q] + sqrtf(fmaxf(lds_quad[row][q], 0.f));
            kap = fmaxf(kap, kq);
        }
        lds_alpha[row] = fminf(1.0f / kap, norm);   // kap==0 -> inf -> norm (matches ref)
    }
    __syncthreads();

    // ---- coalesced epilogue: y = z0 + alpha * v_bar + yp (NA_E = I) ----
#pragma unroll
    for (int i = 0; i < 4; ++i) {
        int idx = tid + i * 256;
        int row = idx >> 4;
        int col0 = (idx & 15) * 8;
        float alpha = lds_alpha[row];
        short8 r8 = *reinterpret_cast<const short8*>(
            lds_rho + row * 256 + ((col0 * 2) ^ ((row & 7) << 4)));
        float yv[8];
#pragma unroll
        for (int j = 0; j < 8; ++j) {
            float vb = bf2f((unsigned short)r8[j]);
            yv[j] = ldf<DT>(z0p, col0 + j) + alpha * vb + ldf<DT>(ypp, col0 + j);
        }
        size_t obase = (row0 + row) * 128 + col0;
        if constexpr (DT == 1) {
            short8 pack;
#pragma unroll
            for (int j = 0; j < 8; ++j) pack[j] = (short)f2bf(yv[j]);
            *reinterpret_cast<short8*>(reinterpret_cast<unsigned short*>(outp) + obase) = pack;
        } else {
            f32x4 p0, p1;
#pragma unroll
            for (int j = 0; j < 4; ++j) { p0[j] = yv[j]; p1[j] = yv[4 + j]; }
            *reinterpret_cast<f32x4*>(reinterpret_cast<float*>(outp) + obase) = p0;
            *reinterpret_cast<f32x4*>(reinterpret_cast<float*>(outp) + obase + 4) = p1;
        }
    }
}

extern "C" void kernel_launch(void* const* d_in, const int* in_sizes, int n_in,
                              void* d_out, int out_size, void* d_ws, size_t ws_size,
                              hipStream_t stream) {
    const void* x    = d_in[0];
    const void* W    = d_in[1];
    const void* b    = d_in[2];
    const void* D    = d_in[3];
    // d_in[4] = NA_E (identity by construction; unused)
    const void* yp   = d_in[5];
    const void* z0   = d_in[6];
    const void* phi  = d_in[7];
    const void* dlt  = d_in[8];
    int* flag = reinterpret_cast<int*>(d_ws);

    const int B = in_sizes[0] / 256;    // 32768
    dim3 grid(B / 64), blk(256);

    detect_dtype<<<dim3(1), dim3(256), 0, stream>>>(
        reinterpret_cast<const unsigned short*>(x), flag);
    rayen_fused<1><<<grid, blk, 0, stream>>>(x, W, b, D, yp, z0, phi, dlt, d_out, flag);
    rayen_fused<0><<<grid, blk, 0, stream>>>(x, W, b, D, yp, z0, phi, dlt, d_out, flag);
}

// Round 7
// 127.698 us; speedup vs baseline: 1.4719x; 1.1565x over previous
//
#include <hip/hip_runtime.h>
#include <hip/hip_bf16.h>

// RAYEN ConstraintModule fused kernel for MI355X (gfx950).
// B=32768, IN_DIM=256, N=K=128, M_LIN=1024, QC=16. bf16 buffers (detector-routed).
// R6: (a) barrier-free panel loop — frag-major layout means each wave consumes only
// its private 4KB quarter-panel, so each wave stages its own quarter via
// global_load_lds into wave-private 3x4KB buffers; vmcnt is per-wave; NO barriers
// in the loop. (b) ABLATION round: distinctly-named variants (nopanel / stageonly /
// mfmaonly) launched before the full kernel to get per-phase dur_us from rocprof.
// R0/R3/R5 all ~145-150us with 3 different panel structures -> bottleneck unproven.

typedef __attribute__((ext_vector_type(8))) short short8;
typedef __attribute__((ext_vector_type(4))) float f32x4;

__device__ __forceinline__ float bf2f(unsigned short u) {
    union { unsigned int i; float f; } v; v.i = ((unsigned int)u) << 16; return v.f;
}
__device__ __forceinline__ unsigned short f2bf(float f) {
    union { float f; unsigned int i; } v; v.f = f;
    unsigned int r = v.i + 0x7FFFu + ((v.i >> 16) & 1u);  // RNE
    return (unsigned short)(r >> 16);
}

template<int DT>
__device__ __forceinline__ short8 ld8(const void* p, size_t i) {
    if constexpr (DT == 1) {
        return *reinterpret_cast<const short8*>(reinterpret_cast<const unsigned short*>(p) + i);
    } else {
        const float* f = reinterpret_cast<const float*>(p) + i;
        short8 r;
#pragma unroll
        for (int j = 0; j < 8; ++j) r[j] = (short)f2bf(f[j]);
        return r;
    }
}
template<int DT>
__device__ __forceinline__ float ldf(const void* p, int i) {
    if constexpr (DT == 1) return bf2f(reinterpret_cast<const unsigned short*>(p)[i]);
    else return reinterpret_cast<const float*>(p)[i];
}

__device__ __forceinline__ void glds16(const void* g, void* l) {
    __builtin_amdgcn_global_load_lds(
        (const __attribute__((address_space(1))) void*)g,
        (__attribute__((address_space(3))) void*)l, 16, 0, 0);
}

__global__ void detect_dtype(const unsigned short* __restrict__ x, int* __restrict__ flag) {
    __shared__ int cnt;
    if (threadIdx.x == 0) cnt = 0;
    __syncthreads();
    float a = fabsf(bf2f(x[threadIdx.x]));
    int ok = (a > 1e-3f && a < 1e2f) ? 1 : 0;
    atomicAdd(&cnt, ok);
    __syncthreads();
    if (threadIdx.x == 0) *flag = (cnt > 200) ? 1 : 0;  // 1 = bf16, 0 = f32
}

// MODE: 0 = full, 1 = no panel loop, 2 = stage+waits only, 3 = stage+MFMA+dmax only
template<int DT, int MODE>
__device__ __forceinline__ void rayen_body(
    const void* xp, const void* Wp, const void* bp, const void* Dp,
    const void* ypp, const void* z0p, const void* phip, const void* dltp,
    void* outp, const int* flag)
{
    if (*flag != DT) return;

    __shared__ unsigned char lds_big[49152];    // x frags (32KB); then 4 waves x 3x4KB bufs
    __shared__ unsigned char lds_rho[16384];    // rho [64][256B], XOR-swizzled rows
    __shared__ float lds_nsq[64][4];
    __shared__ float lds_dmax[64][4];
    __shared__ float lds_quad[64][16];
    __shared__ float lds_lin[64][16];
    __shared__ float lds_alpha[64];

    const int tid = threadIdx.x;
    const int lane = tid & 63;
    const int w = tid >> 6;        // wave 0..3
    const int hi = lane >> 4;      // 0..3
    const int lo = lane & 15;      // 0..15
    const size_t row0 = (size_t)blockIdx.x * 64;

    const unsigned char* Xb = (const unsigned char*)xp;
    const unsigned char* Db = (const unsigned char*)Dp;
    const unsigned char* Qb = (const unsigned char*)dltp;

    // ---- stage x tile [64][256] bf16, fragment-major: frag f = rt*8+kb ----
#pragma unroll
    for (int i = 0; i < 8; ++i) {
        int ch = i * 256 + tid;
        int row = ((ch >> 9) << 4) | (ch & 15);
        int off = (((ch >> 6) & 7) << 6) | (((ch >> 4) & 3) << 4);
        if constexpr (DT == 1)
            glds16(Xb + (row0 + row) * 512 + off, lds_big + ch * 16);
        else {
            short8 v = ld8<0>(Xb, (row0 + row) * 256 + (off >> 1));
            *reinterpret_cast<short8*>(lds_big + ch * 16) = v;
        }
    }

    short8 wf[2][8];
#pragma unroll
    for (int ct = 0; ct < 2; ++ct)
#pragma unroll
        for (int kb = 0; kb < 8; ++kb)
            wf[ct][kb] = ld8<DT>(Wp, (size_t)(w * 32 + ct * 16 + lo) * 256 + kb * 32 + hi * 8);

    asm volatile("s_waitcnt vmcnt(0)" ::: "memory");
    __syncthreads();

    // ---- GEMM1: v[64][128] = x @ W^T; wave w: cols [w*32, w*32+32) ----
    f32x4 acc1[2][4];
#pragma unroll
    for (int c = 0; c < 2; ++c)
#pragma unroll
        for (int r = 0; r < 4; ++r)
#pragma unroll
            for (int e = 0; e < 4; ++e) acc1[c][r][e] = 0.f;

#pragma unroll
    for (int kb = 0; kb < 8; ++kb) {
        short8 af[4];
#pragma unroll
        for (int rt = 0; rt < 4; ++rt)
            af[rt] = *reinterpret_cast<const short8*>(
                lds_big + (((rt << 3) | kb) << 10) + lane * 16);
#pragma unroll
        for (int ct = 0; ct < 2; ++ct)
#pragma unroll
            for (int rt = 0; rt < 4; ++rt)
                acc1[ct][rt] = __builtin_amdgcn_mfma_f32_16x16x32_bf16(af[rt], wf[ct][kb], acc1[ct][rt], 0, 0, 0);
    }

    float bv[2];
#pragma unroll
    for (int ct = 0; ct < 2; ++ct) bv[ct] = ldf<DT>(bp, w * 32 + ct * 16 + lo);
#pragma unroll
    for (int rt = 0; rt < 4; ++rt)
#pragma unroll
        for (int reg = 0; reg < 4; ++reg) {
            float s = 0.f;
#pragma unroll
            for (int ct = 0; ct < 2; ++ct) {
                float v = acc1[ct][rt][reg] + bv[ct];
                acc1[ct][rt][reg] = v;
                s += v * v;
            }
            s += __shfl_xor(s, 1);
            s += __shfl_xor(s, 2);
            s += __shfl_xor(s, 4);
            s += __shfl_xor(s, 8);
            if (lo == 0) lds_nsq[rt * 16 + hi * 4 + reg][w] = s;
        }
    __syncthreads();   // all x reads done; lds_big free for panel staging

    // ---- v_bar -> swizzled bf16 rho ----
#pragma unroll
    for (int rt = 0; rt < 4; ++rt)
#pragma unroll
        for (int reg = 0; reg < 4; ++reg) {
            int row = rt * 16 + hi * 4 + reg;
            float nsq = lds_nsq[row][0] + lds_nsq[row][1] + lds_nsq[row][2] + lds_nsq[row][3];
            float rinv = 1.0f / fmaxf(sqrtf(nsq), 1e-12f);
#pragma unroll
            for (int ct = 0; ct < 2; ++ct) {
                int col = w * 32 + ct * 16 + lo;
                unsigned short u = f2bf(acc1[ct][rt][reg] * rinv);
                *reinterpret_cast<unsigned short*>(
                    lds_rho + row * 256 + ((col * 2) ^ ((row & 7) << 4))) = u;
            }
        }
    __syncthreads();

    // ---- A-fragments (rho) resident: 64 VGPRs ----
    short8 af2[4][4];
#pragma unroll
    for (int rt = 0; rt < 4; ++rt)
#pragma unroll
        for (int kb = 0; kb < 4; ++kb) {
            int row = rt * 16 + lo;
            af2[rt][kb] = *reinterpret_cast<const short8*>(
                lds_rho + row * 256 + (((kb << 6) | (hi << 4)) ^ ((lo & 7) << 4)));
        }

    // ---- wave-private panel staging: wave w owns rows [w*16, w*16+16) of each panel ----
    unsigned char* wbase = lds_big + w * 12288;   // 3 bufs x 4KB
    auto stage_q = [&](int p, int b) {
        unsigned char* dst0 = wbase + b * 4096;
#pragma unroll
        for (int kb = 0; kb < 4; ++kb) {
            size_t grow;
            const void* base;
            if (p < 16) { base = Dp;   grow = (size_t)(p * 64 + w * 16 + lo); }
            else {
                int pd = p - 16;
                base = dltp;
                grow = (size_t)((((pd >> 3) * 4 + w) * 128) + ((pd & 7) * 16 + lo));
            }
            if constexpr (DT == 1)
                glds16((const unsigned char*)base + grow * 256 + kb * 64 + hi * 16,
                       dst0 + kb * 1024);
            else {
                short8 v = ld8<0>(base, grow * 128 + kb * 32 + hi * 8);
                *reinterpret_cast<short8*>(dst0 + kb * 1024 + lane * 16) = v;
            }
        }
    };

    f32x4 dmax[4];
#pragma unroll
    for (int rt = 0; rt < 4; ++rt)
#pragma unroll
        for (int e = 0; e < 4; ++e) dmax[rt][e] = -3e38f;
    f32x4 qsum[4];
#pragma unroll
    for (int rt = 0; rt < 4; ++rt)
#pragma unroll
        for (int e = 0; e < 4; ++e) qsum[rt][e] = 0.f;

    if constexpr (MODE != 1) {
        stage_q(0, 0);
        stage_q(1, 1);
#pragma unroll 1
        for (int p = 0; p < 48; ++p) {
            if constexpr (DT == 1) {
                if (p < 47) { asm volatile("s_waitcnt vmcnt(4)" ::: "memory"); }
                else        { asm volatile("s_waitcnt vmcnt(0)" ::: "memory"); }
            } else {
                asm volatile("s_waitcnt vmcnt(0) lgkmcnt(0)" ::: "memory");
            }
            __builtin_amdgcn_sched_barrier(0);
            if (p + 2 < 48) stage_q(p + 2, (p + 2) % 3);

            if constexpr (MODE != 2) {
                unsigned char* buf = wbase + (p % 3) * 4096;
                f32x4 acc[4];
#pragma unroll
                for (int rt = 0; rt < 4; ++rt)
#pragma unroll
                    for (int e = 0; e < 4; ++e) acc[rt][e] = 0.f;
#pragma unroll
                for (int kb = 0; kb < 4; ++kb) {
                    short8 bf = *reinterpret_cast<const short8*>(buf + kb * 1024 + lane * 16);
#pragma unroll
                    for (int rt = 0; rt < 4; ++rt)
                        acc[rt] = __builtin_amdgcn_mfma_f32_16x16x32_bf16(af2[rt][kb], bf, acc[rt], 0, 0, 0);
                }

                if (MODE == 3 || p < 16) {
#pragma unroll
                    for (int rt = 0; rt < 4; ++rt)
#pragma unroll
                        for (int e = 0; e < 4; ++e) dmax[rt][e] = fmaxf(dmax[rt][e], acc[rt][e]);
                } else {
                    int pd = p - 16;
                    int kr = (pd & 7) << 4;
#pragma unroll
                    for (int rt = 0; rt < 4; ++rt)
#pragma unroll
                        for (int e = 0; e < 4; ++e) {
                            int row = rt * 16 + hi * 4 + e;
                            float rvv = bf2f(*reinterpret_cast<const unsigned short*>(
                                lds_rho + row * 256 + ((((kr + lo) * 2)) ^ ((row & 7) << 4))));
                            qsum[rt][e] += acc[rt][e] * rvv;
                        }
                    if ((pd & 7) == 7) {
#pragma unroll
                        for (int rt = 0; rt < 4; ++rt)
#pragma unroll
                            for (int e = 0; e < 4; ++e) {
                                float s = qsum[rt][e];
                                s += __shfl_xor(s, 1);
                                s += __shfl_xor(s, 2);
                                s += __shfl_xor(s, 4);
                                s += __shfl_xor(s, 8);
                                if (lo == 0) lds_quad[rt * 16 + hi * 4 + e][((pd >> 3) << 2) | w] = s;
                                qsum[rt][e] = 0.f;
                            }
                    }
                }
            }
        }
    }

    // ---- flush / ablation-fill of dmax & quad ----
    if constexpr (MODE == 0 || MODE == 3) {
#pragma unroll
        for (int rt = 0; rt < 4; ++rt)
#pragma unroll
            for (int reg = 0; reg < 4; ++reg) {
                float m = dmax[rt][reg];
                m = fmaxf(m, __shfl_xor(m, 1));
                m = fmaxf(m, __shfl_xor(m, 2));
                m = fmaxf(m, __shfl_xor(m, 4));
                m = fmaxf(m, __shfl_xor(m, 8));
                if (lo == 0) lds_dmax[rt * 16 + hi * 4 + reg][w] = m;
            }
    }
    if constexpr (MODE == 1 || MODE == 2) {
        if (tid < 64) {
#pragma unroll
            for (int j = 0; j < 4; ++j) lds_dmax[tid][j] = 0.f;
        }
    }
    if constexpr (MODE != 0) {
        if (tid < 64) {
#pragma unroll
            for (int q = 0; q < 16; ++q) lds_quad[tid][q] = 0.f;
        }
    }

    // ---- phi (wave 0): lin[b,q] = rho . phi_q  (keeps af2/rho/GEMM1 live in ablations) ----
    if (w == 0) {
        f32x4 accp[4];
#pragma unroll
        for (int rt = 0; rt < 4; ++rt)
#pragma unroll
            for (int e = 0; e < 4; ++e) accp[rt][e] = 0.f;
#pragma unroll
        for (int kb = 0; kb < 4; ++kb) {
            short8 bp8 = ld8<DT>(phip, (size_t)lo * 128 + kb * 32 + hi * 8);
#pragma unroll
            for (int rt = 0; rt < 4; ++rt)
                accp[rt] = __builtin_amdgcn_mfma_f32_16x16x32_bf16(af2[rt][kb], bp8, accp[rt], 0, 0, 0);
        }
#pragma unroll
        for (int rt = 0; rt < 4; ++rt)
#pragma unroll
            for (int reg = 0; reg < 4; ++reg)
                lds_lin[rt * 16 + hi * 4 + reg][lo] = accp[rt][reg];
    }
    __syncthreads();

    // ---- per-row scalars: kappa, alpha ----
    if (tid < 64) {
        int row = tid;
        float nsq = lds_nsq[row][0] + lds_nsq[row][1] + lds_nsq[row][2] + lds_nsq[row][3];
        float norm = sqrtf(nsq);
        float kap = fmaxf(0.f, fmaxf(fmaxf(lds_dmax[row][0], lds_dmax[row][1]),
                                     fmaxf(lds_dmax[row][2], lds_dmax[row][3])));
#pragma unroll
        for (int q = 0; q < 16; ++q) {
            float kq = lds_lin[row][q] + sqrtf(fmaxf(lds_quad[row][q], 0.f));
            kap = fmaxf(kap, kq);
        }
        lds_alpha[row] = fminf(1.0f / kap, norm);   // kap==0 -> inf -> norm (matches ref)
    }
    __syncthreads();

    // ---- coalesced epilogue: y = z0 + alpha * v_bar + yp (NA_E = I) ----
#pragma unroll
    for (int i = 0; i < 4; ++i) {
        int idx = tid + i * 256;
        int row = idx >> 4;
        int col0 = (idx & 15) * 8;
        float alpha = lds_alpha[row];
        short8 r8 = *reinterpret_cast<const short8*>(
            lds_rho + row * 256 + ((col0 * 2) ^ ((row & 7) << 4)));
        float yv[8];
#pragma unroll
        for (int j = 0; j < 8; ++j) {
            float vb = bf2f((unsigned short)r8[j]);
            yv[j] = ldf<DT>(z0p, col0 + j) + alpha * vb + ldf<DT>(ypp, col0 + j);
        }
        size_t obase = (row0 + row) * 128 + col0;
        if constexpr (DT == 1) {
            short8 pack;
#pragma unroll
            for (int j = 0; j < 8; ++j) pack[j] = (short)f2bf(yv[j]);
            *reinterpret_cast<short8*>(reinterpret_cast<unsigned short*>(outp) + obase) = pack;
        } else {
            f32x4 p0, p1;
#pragma unroll
            for (int j = 0; j < 4; ++j) { p0[j] = yv[j]; p1[j] = yv[4 + j]; }
            *reinterpret_cast<f32x4*>(reinterpret_cast<float*>(outp) + obase) = p0;
            *reinterpret_cast<f32x4*>(reinterpret_cast<float*>(outp) + obase + 4) = p1;
        }
    }
}

#define ARGS const void* xp, const void* Wp, const void* bp, const void* Dp, \
             const void* ypp, const void* z0p, const void* phip, const void* dltp, \
             void* outp, const int* flag
#define PASS xp, Wp, bp, Dp, ypp, z0p, phip, dltp, outp, flag

template<int DT>
__global__ __launch_bounds__(256, 2) void rayen_full(ARGS)      { rayen_body<DT, 0>(PASS); }
__global__ __launch_bounds__(256, 2) void rayen_abl_nopanel(ARGS)   { rayen_body<1, 1>(PASS); }
__global__ __launch_bounds__(256, 2) void rayen_abl_stageonly(ARGS) { rayen_body<1, 2>(PASS); }
__global__ __launch_bounds__(256, 2) void rayen_abl_mfmaonly(ARGS)  { rayen_body<1, 3>(PASS); }

extern "C" void kernel_launch(void* const* d_in, const int* in_sizes, int n_in,
                              void* d_out, int out_size, void* d_ws, size_t ws_size,
                              hipStream_t stream) {
    const void* x    = d_in[0];
    const void* W    = d_in[1];
    const void* b    = d_in[2];
    const void* D    = d_in[3];
    // d_in[4] = NA_E (identity by construction; unused)
    const void* yp   = d_in[5];
    const void* z0   = d_in[6];
    const void* phi  = d_in[7];
    const void* dlt  = d_in[8];
    int* flag = reinterpret_cast<int*>(d_ws);

    const int B = in_sizes[0] / 256;    // 32768
    dim3 grid(B / 64), blk(256);

    detect_dtype<<<dim3(1), dim3(256), 0, stream>>>(
        reinterpret_cast<const unsigned short*>(x), flag);
    // ablation probes (bf16 path only; outputs overwritten by rayen_full below)
    rayen_abl_nopanel<<<grid, blk, 0, stream>>>(x, W, b, D, yp, z0, phi, dlt, d_out, flag);
    rayen_abl_stageonly<<<grid, blk, 0, stream>>>(x, W, b, D, yp, z0, phi, dlt, d_out, flag);
    rayen_abl_mfmaonly<<<grid, blk, 0, stream>>>(x, W, b, D, yp, z0, phi, dlt, d_out, flag);
    // the real kernel (last writer of d_out)
    rayen_full<1><<<grid, blk, 0, stream>>>(x, W, b, D, yp, z0, phi, dlt, d_out, flag);
    rayen_full<0><<<grid, blk, 0, stream>>>(x, W, b, D, yp, z0, phi, dlt, d_out, flag);
}